// Round 7
// baseline (288.139 us; speedup 1.0000x reference)
//
#include <hip/hip_runtime.h>
#include <math.h>
#include <stdint.h>

static constexpr int NN = 50000;   // nodes
static constexpr int NE = 800000;  // edges
static constexpr int NG = 512;     // graphs
static constexpr int NB = (NN + 255) / 256;  // 196 scan blocks
static constexpr float BNEPS = 1e-5f;

typedef __bf16 bf16x8 __attribute__((ext_vector_type(8)));
typedef __bf16 bf16x2 __attribute__((ext_vector_type(2)));
typedef float f32x4 __attribute__((ext_vector_type(4)));

__device__ __forceinline__ uint32_t pack_bf16(float x, float y) {
    bf16x2 v; v[0] = (__bf16)x; v[1] = (__bf16)y;
    return __builtin_bit_cast(uint32_t, v);
}
__device__ __forceinline__ float2 unpack_bf16(uint32_t u) {
    bf16x2 v = __builtin_bit_cast(bf16x2, u);
    return make_float2((float)v[0], (float)v[1]);
}

// ---------------- CSR build ----------------

// degree + per-edge rank in one pass (rank = position within dst's row)
__global__ void degree_kernel(const int* __restrict__ dst, int* __restrict__ deg,
                              uint16_t* __restrict__ rank) {
    int e = blockIdx.x * blockDim.x + threadIdx.x;
    if (e < NE) rank[e] = (uint16_t)atomicAdd(&deg[dst[e]], 1);
}

// phase A: per-block (256 nodes) sum of degrees
__global__ __launch_bounds__(256) void blocksum_kernel(const int* __restrict__ deg,
                                                       int* __restrict__ bsum) {
    int i = blockIdx.x * 256 + threadIdx.x;
    int v = (i < NN) ? deg[i] : 0;
#pragma unroll
    for (int off = 32; off; off >>= 1) v += __shfl_down(v, off, 64);
    __shared__ int s[4];
    if ((threadIdx.x & 63) == 0) s[threadIdx.x >> 6] = v;
    __syncthreads();
    if (threadIdx.x == 0) bsum[blockIdx.x] = s[0] + s[1] + s[2] + s[3];
}

// phase B: exclusive scan of NB block sums (single small block)
__global__ __launch_bounds__(256) void scanb_kernel(const int* __restrict__ bsum,
                                                    int* __restrict__ bscan,
                                                    int* __restrict__ row_ptr) {
    __shared__ int s[256];
    int t = threadIdx.x;
    int v = (t < NB) ? bsum[t] : 0;
    s[t] = v;
    __syncthreads();
    for (int off = 1; off < 256; off <<= 1) {
        int u = (t >= off) ? s[t - off] : 0;
        __syncthreads();
        s[t] += u;
        __syncthreads();
    }
    if (t < NB) bscan[t] = s[t] - v;  // exclusive
    if (t == NB - 1) row_ptr[NN] = s[t];
}

// phase C: per-block exclusive scan + global offset -> row_ptr
__global__ __launch_bounds__(256) void scanfinal_kernel(const int* __restrict__ deg,
                                                        const int* __restrict__ bscan,
                                                        int* __restrict__ row_ptr) {
    __shared__ int s[256];
    int t = threadIdx.x;
    int i = blockIdx.x * 256 + t;
    int v = (i < NN) ? deg[i] : 0;
    s[t] = v;
    __syncthreads();
    for (int off = 1; off < 256; off <<= 1) {
        int u = (t >= off) ? s[t - off] : 0;
        __syncthreads();
        s[t] += u;
        __syncthreads();
    }
    if (i < NN) row_ptr[i] = bscan[blockIdx.x] + s[t] - v;
}

// atomic-free fill using precomputed rank; cols are u16 (N < 65536)
__global__ void fill_kernel(const int* __restrict__ src, const int* __restrict__ dst,
                            const int* __restrict__ row_ptr, const uint16_t* __restrict__ rank,
                            uint16_t* __restrict__ cols) {
    int e = blockIdx.x * blockDim.x + threadIdx.x;
    if (e < NE) cols[row_ptr[dst[e]] + (int)rank[e]] = (uint16_t)src[e];
}

// ---------------- prep: x fp32->bf16 + all weight transposes, one kernel ----------------

__global__ void prep_kernel(const float* __restrict__ x, __bf16* __restrict__ xb,
                            const float* s0, const float* s1, const float* s2,
                            const float* s3, const float* s4, const float* s5,
                            const float* s6,
                            __bf16* d0, __bf16* d1, __bf16* d2,
                            __bf16* d3, __bf16* d4, __bf16* d5, __bf16* d6) {
    int i = blockIdx.x * blockDim.x + threadIdx.x;
    if (i < 800000) {
        float4 v = *(const float4*)&x[i * 4];
        xb[i * 4 + 0] = (__bf16)v.x;
        xb[i * 4 + 1] = (__bf16)v.y;
        xb[i * 4 + 2] = (__bf16)v.z;
        xb[i * 4 + 3] = (__bf16)v.w;
        return;
    }
    int j = i - 800000;
    if (j < 8192) {
        int l = j;           int n = l / 64,  k = l % 64;  d0[l] = (__bf16)s0[k * 128 + n];
    } else if (j < 24576) {
        int l = j - 8192;    int n = l / 128, k = l % 128; d1[l] = (__bf16)s1[k * 128 + n];
    } else if (j < 40960) {
        int l = j - 24576;   int n = l / 128, k = l % 128; d2[l] = (__bf16)s2[k * 128 + n];
    } else if (j < 57344) {
        int l = j - 40960;   int n = l / 128, k = l % 128; d3[l] = (__bf16)s3[k * 128 + n];
    } else if (j < 73728) {
        int l = j - 57344;   int n = l / 128, k = l % 128; d4[l] = (__bf16)s4[k * 128 + n];
    } else if (j < 90112) {
        int l = j - 73728;   int n = l / 128, k = l % 128; d5[l] = (__bf16)s5[k * 128 + n];
    } else if (j < 237568) {
        int l = j - 90112;   int n = l / 384, k = l % 384; d6[l] = (__bf16)s6[k * 384 + n];
    }
}

// ---------------- gather, feature-slice passes ----------------
// Pass f reads only 32 features (16 dwords, 64 B) per row -> per-pass working set
// 50000*64B = 3.2 MB < 4 MB per-XCD L2 -> random reads become L2 hits.
// 16 lanes per node (1 dword each), 4 nodes per wave, 8 waves per block.
// grid: dim3(ceil(NN/32), DWPR/16) with x fastest so same-pass blocks co-reside.

template <int DWPR>  // dwords per row: 32 for 64-dim, 64 for 128-dim
__global__ __launch_bounds__(512) void gather_pass_kernel(const __bf16* __restrict__ in,
                                                          const int* __restrict__ row_ptr,
                                                          const uint16_t* __restrict__ cols,
                                                          __bf16* __restrict__ agg) {
    int wid = threadIdx.x >> 6;
    int sub = (threadIdx.x & 63) >> 4;   // node within wave: 0..3
    int l16 = threadIdx.x & 15;          // dword within slice: 0..15
    int node = (blockIdx.x * 8 + wid) * 4 + sub;
    if (node >= NN) return;
    int off = blockIdx.y * 16 + l16;     // dword offset within row
    const uint32_t* inu = (const uint32_t*)in;
    uint32_t* aggu = (uint32_t*)agg;
    int beg = row_ptr[node], end = row_ptr[node + 1];
    float2 a0 = unpack_bf16(inu[(size_t)node * DWPR + off]);
    float2 a1 = make_float2(0.f, 0.f);
    int i = beg;
    for (; i + 4 <= end; i += 4) {
        int c0 = cols[i], c1 = cols[i + 1], c2 = cols[i + 2], c3 = cols[i + 3];
        uint32_t u0 = inu[(size_t)c0 * DWPR + off];
        uint32_t u1 = inu[(size_t)c1 * DWPR + off];
        uint32_t u2 = inu[(size_t)c2 * DWPR + off];
        uint32_t u3 = inu[(size_t)c3 * DWPR + off];
        float2 v0 = unpack_bf16(u0), v1 = unpack_bf16(u1);
        float2 v2 = unpack_bf16(u2), v3 = unpack_bf16(u3);
        a0.x += v0.x + v1.x; a0.y += v0.y + v1.y;
        a1.x += v2.x + v3.x; a1.y += v2.y + v3.y;
    }
    for (; i < end; ++i) {
        float2 v = unpack_bf16(inu[(size_t)cols[i] * DWPR + off]);
        a0.x += v.x; a0.y += v.y;
    }
    aggu[(size_t)node * DWPR + off] = pack_bf16(a0.x + a1.x, a0.y + a1.y);
}

// ---------------- fused MLP via MFMA + pooling epilogue ----------------

template <int K, bool WOUT>
__global__ __launch_bounds__(512, 1) void mlp_mfma_kernel(
    const __bf16* __restrict__ agg,   // [NN][K] bf16
    const __bf16* __restrict__ w1t,   // [128][K] bf16 (transposed)
    const float* __restrict__ b1,
    const float* __restrict__ g, const float* __restrict__ be,
    const float* __restrict__ m, const float* __restrict__ v,
    const __bf16* __restrict__ w2t,   // [128][128] bf16 (transposed)
    const float* __restrict__ b2,
    __bf16* __restrict__ out,         // [NN][128] bf16 (unused if !WOUT)
    const int* __restrict__ batch,    // [NN] sorted graph ids
    float* __restrict__ p,            // [NG][384] pooled accumulator
    int col_off)
{
    constexpr int KP = K + 8;
    constexpr int KP2 = 136;
    __shared__ alignas(16) __bf16 sA[64 * KP];
    __shared__ alignas(16) __bf16 sW1[128 * KP];
    __shared__ alignas(16) __bf16 sW2[128 * KP2];
    __shared__ alignas(16) __bf16 sT[64 * KP2];
    __shared__ alignas(16) __bf16 sOut[64 * KP2];
    __shared__ int sBatch[64];

    int tid = threadIdx.x;
    int wid = tid >> 6, lane = tid & 63;
    int wr = wid >> 1, wc = wid & 1;
    int l15 = lane & 15, lq = lane >> 4;
    int rowbase = blockIdx.x * 64;

    for (int idx = tid; idx < 64 * (K / 8); idx += 512) {
        int r = idx / (K / 8), kc = idx % (K / 8);
        int n = rowbase + r;
        uint4 val = make_uint4(0, 0, 0, 0);
        if (n < NN) val = *(const uint4*)&agg[(size_t)n * K + kc * 8];
        *(uint4*)&sA[r * KP + kc * 8] = val;
    }
    for (int idx = tid; idx < 128 * (K / 8); idx += 512) {
        int n = idx / (K / 8), kc = idx % (K / 8);
        *(uint4*)&sW1[n * KP + kc * 8] = *(const uint4*)&w1t[n * K + kc * 8];
    }
    for (int idx = tid; idx < 128 * 16; idx += 512) {
        int n = idx >> 4, kc = idx & 15;
        *(uint4*)&sW2[n * KP2 + kc * 8] = *(const uint4*)&w2t[n * 128 + kc * 8];
    }
    if (tid < 64) {
        int n = rowbase + tid;
        sBatch[tid] = (n < NN) ? batch[n] : -1;
    }
    __syncthreads();

    f32x4 acc[4] = {};
#pragma unroll
    for (int ks = 0; ks < K / 32; ++ks) {
        bf16x8 a = *(const bf16x8*)&sA[(wr * 16 + l15) * KP + ks * 32 + lq * 8];
#pragma unroll
        for (int nf = 0; nf < 4; ++nf) {
            bf16x8 b = *(const bf16x8*)&sW1[(wc * 64 + nf * 16 + l15) * KP + ks * 32 + lq * 8];
            acc[nf] = __builtin_amdgcn_mfma_f32_16x16x32_bf16(a, b, acc[nf], 0, 0, 0);
        }
    }
#pragma unroll
    for (int nf = 0; nf < 4; ++nf) {
        int c = wc * 64 + nf * 16 + l15;
        float sc = g[c] * rsqrtf(v[c] + BNEPS);
        float sh = be[c] + (b1[c] - m[c]) * sc;
#pragma unroll
        for (int r = 0; r < 4; ++r) {
            int row = wr * 16 + lq * 4 + r;
            float t = fmaxf(acc[nf][r] * sc + sh, 0.f);
            sT[row * KP2 + c] = (__bf16)t;
        }
    }
    __syncthreads();

    f32x4 acc2[4] = {};
#pragma unroll
    for (int ks = 0; ks < 4; ++ks) {
        bf16x8 a = *(const bf16x8*)&sT[(wr * 16 + l15) * KP2 + ks * 32 + lq * 8];
#pragma unroll
        for (int nf = 0; nf < 4; ++nf) {
            bf16x8 b = *(const bf16x8*)&sW2[(wc * 64 + nf * 16 + l15) * KP2 + ks * 32 + lq * 8];
            acc2[nf] = __builtin_amdgcn_mfma_f32_16x16x32_bf16(a, b, acc2[nf], 0, 0, 0);
        }
    }
#pragma unroll
    for (int nf = 0; nf < 4; ++nf) {
        int c = wc * 64 + nf * 16 + l15;
        float bb = b2[c];
#pragma unroll
        for (int r = 0; r < 4; ++r) {
            int row = wr * 16 + lq * 4 + r;
            float o = fmaxf(acc2[nf][r] + bb, 0.f);
            sOut[row * KP2 + c] = (__bf16)o;
        }
    }
    __syncthreads();

    if constexpr (WOUT) {
        for (int idx = tid; idx < 64 * 16; idx += 512) {
            int r = idx >> 4, kc = idx & 15;
            int n = rowbase + r;
            if (n < NN)
                *(uint4*)&out[(size_t)n * 128 + kc * 8] = *(const uint4*)&sOut[r * KP2 + kc * 8];
        }
    }

    {
        int f = tid & 127;
        int chunk = tid >> 7;
        float pacc = 0.f;
        int cur = -1;
#pragma unroll
        for (int i = 0; i < 16; ++i) {
            int row = chunk * 16 + i;
            int b = sBatch[row];
            if (b < 0) break;
            if (b != cur) {
                if (cur >= 0) atomicAdd(&p[cur * 384 + col_off + f], pacc);
                pacc = 0.f;
                cur = b;
            }
            pacc += (float)sOut[row * KP2 + f];
        }
        if (cur >= 0) atomicAdd(&p[cur * 384 + col_off + f], pacc);
    }
}

// ---------------- head stage 1: hrelu = relu(p @ lin1 + b)  via MFMA ----------------

__global__ __launch_bounds__(512, 1) void head1_kernel(const float* __restrict__ p,
                                                       const __bf16* __restrict__ lin1t,
                                                       const float* __restrict__ b1,
                                                       float* __restrict__ hrelu) {
    constexpr int KPA = 392;   // 384 + 8
    constexpr int KPW = 136;   // 128 + 8
    __shared__ alignas(16) __bf16 sA[64 * KPA];
    __shared__ alignas(16) __bf16 sW[128 * KPW];

    int tid = threadIdx.x;
    int wid = tid >> 6, lane = tid & 63;
    int wr = wid >> 1, wc = wid & 1;
    int l15 = lane & 15, lq = lane >> 4;
    int rowbase = blockIdx.x * 64;     // 0..448
    int colbase = blockIdx.y * 128;    // 0, 128, 256

    for (int idx = tid; idx < 64 * 48; idx += 512) {
        int r = idx / 48, kc = idx % 48;
        const float* srcp = &p[(rowbase + r) * 384 + kc * 8];
        float4 v0 = *(const float4*)srcp;
        float4 v1 = *(const float4*)(srcp + 4);
        bf16x8 o;
        o[0] = (__bf16)v0.x; o[1] = (__bf16)v0.y; o[2] = (__bf16)v0.z; o[3] = (__bf16)v0.w;
        o[4] = (__bf16)v1.x; o[5] = (__bf16)v1.y; o[6] = (__bf16)v1.z; o[7] = (__bf16)v1.w;
        *(bf16x8*)&sA[r * KPA + kc * 8] = o;
    }

    f32x4 acc[4] = {};
#pragma unroll
    for (int kchunk = 0; kchunk < 3; ++kchunk) {
        for (int idx = tid; idx < 128 * 16; idx += 512) {
            int n = idx >> 4, kc = idx & 15;
            *(uint4*)&sW[n * KPW + kc * 8] =
                *(const uint4*)&lin1t[(colbase + n) * 384 + kchunk * 128 + kc * 8];
        }
        __syncthreads();
#pragma unroll
        for (int ks = 0; ks < 4; ++ks) {
            bf16x8 a = *(const bf16x8*)&sA[(wr * 16 + l15) * KPA + kchunk * 128 + ks * 32 + lq * 8];
#pragma unroll
            for (int nf = 0; nf < 4; ++nf) {
                bf16x8 b = *(const bf16x8*)&sW[(wc * 64 + nf * 16 + l15) * KPW + ks * 32 + lq * 8];
                acc[nf] = __builtin_amdgcn_mfma_f32_16x16x32_bf16(a, b, acc[nf], 0, 0, 0);
            }
        }
        __syncthreads();
    }
#pragma unroll
    for (int nf = 0; nf < 4; ++nf) {
        int col = colbase + wc * 64 + nf * 16 + l15;
        float bb = b1[col];
#pragma unroll
        for (int r = 0; r < 4; ++r) {
            int row = rowbase + wr * 16 + lq * 4 + r;
            hrelu[row * 384 + col] = fmaxf(acc[nf][r] + bb, 0.f);
        }
    }
}

// ---------------- head stage 2: logits + log_softmax, one wave per graph ----------------

__global__ __launch_bounds__(256) void head2_kernel(const float* __restrict__ hrelu,
                                                    const float* __restrict__ w2,   // [384][10]
                                                    const float* __restrict__ b2,
                                                    float* __restrict__ out) {
    int wid = threadIdx.x >> 6, lane = threadIdx.x & 63;
    int gidx = blockIdx.x * 4 + wid;   // grid 128 -> 512 graphs
    const float* hr = &hrelu[gidx * 384 + lane * 6];
    float h[6];
#pragma unroll
    for (int u = 0; u < 6; ++u) h[u] = hr[u];
    float logit[10];
#pragma unroll
    for (int c = 0; c < 10; ++c) {
        float s = 0.f;
#pragma unroll
        for (int u = 0; u < 6; ++u) s = fmaf(h[u], w2[(lane * 6 + u) * 10 + c], s);
#pragma unroll
        for (int off = 32; off; off >>= 1) s += __shfl_xor(s, off, 64);
        logit[c] = s + b2[c];
    }
    float mx = logit[0];
#pragma unroll
    for (int c = 1; c < 10; ++c) mx = fmaxf(mx, logit[c]);
    float se = 0.f;
#pragma unroll
    for (int c = 0; c < 10; ++c) se += expf(logit[c] - mx);
    float lse = logf(se);
    float val = 0.f;
#pragma unroll
    for (int c = 0; c < 10; ++c) if (lane == c) val = logit[c];
    if (lane < 10) out[gidx * 10 + lane] = val - mx - lse;
}

// ---------------- launch ----------------

static inline char* align_up(char* ptr, size_t a) {
    return (char*)(((uintptr_t)ptr + a - 1) & ~(uintptr_t)(a - 1));
}

extern "C" void kernel_launch(void* const* d_in, const int* in_sizes, int n_in,
                              void* d_out, int out_size, void* d_ws, size_t ws_size,
                              hipStream_t stream) {
    const float* x = (const float*)d_in[0];
    const int* ei = (const int*)d_in[1];
    const int* batch = (const int*)d_in[2];
    const float* c_w1[3], *c_b1[3], *c_g[3], *c_be[3], *c_m[3], *c_v[3], *c_w2[3], *c_b2[3];
    for (int i = 0; i < 3; ++i) {
        int base = 3 + i * 8;
        c_w1[i] = (const float*)d_in[base + 0];
        c_b1[i] = (const float*)d_in[base + 1];
        c_g[i]  = (const float*)d_in[base + 2];
        c_be[i] = (const float*)d_in[base + 3];
        c_m[i]  = (const float*)d_in[base + 4];
        c_v[i]  = (const float*)d_in[base + 5];
        c_w2[i] = (const float*)d_in[base + 6];
        c_b2[i] = (const float*)d_in[base + 7];
    }
    const float* lin1_w = (const float*)d_in[27];
    const float* lin1_b = (const float*)d_in[28];
    const float* lin2_w = (const float*)d_in[29];
    const float* lin2_b = (const float*)d_in[30];
    const int* src = ei;
    const int* dst = ei + NE;
    float* out = (float*)d_out;

    // workspace carve
    char* ws = (char*)d_ws;
    __bf16* xb  = (__bf16*)ws; ws = align_up(ws + (size_t)NN * 64 * 2, 256);
    __bf16* agg = (__bf16*)ws; ws = align_up(ws + (size_t)NN * 128 * 2, 256);
    __bf16* hA  = (__bf16*)ws; ws = align_up(ws + (size_t)NN * 128 * 2, 256);
    __bf16* hB  = (__bf16*)ws; ws = align_up(ws + (size_t)NN * 128 * 2, 256);
    float* p    = (float*)ws;  ws = align_up(ws + (size_t)NG * 384 * 4, 256);
    float* hrelu = (float*)ws; ws = align_up(ws + (size_t)NG * 384 * 4, 256);
    int* csr_row = (int*)ws;   ws = align_up(ws + (size_t)(NN + 1) * 4, 256);
    int* cursor  = (int*)ws;   ws = align_up(ws + (size_t)NN * 4, 256);
    uint16_t* csr_src = (uint16_t*)ws; ws = align_up(ws + (size_t)NE * 2, 256);
    uint16_t* rank    = (uint16_t*)ws; ws = align_up(ws + (size_t)NE * 2, 256);
    int* bsum    = (int*)ws;   ws = align_up(ws + (size_t)NB * 4, 256);
    int* bscan   = (int*)ws;   ws = align_up(ws + (size_t)NB * 4, 256);
    __bf16* w1t[3]; __bf16* w2t[3];
    for (int i = 0; i < 3; ++i) {
        int K = (i == 0) ? 64 : 128;
        w1t[i] = (__bf16*)ws; ws = align_up(ws + (size_t)128 * K * 2, 256);
        w2t[i] = (__bf16*)ws; ws = align_up(ws + (size_t)128 * 128 * 2, 256);
    }
    __bf16* lin1t = (__bf16*)ws; ws = align_up(ws + (size_t)384 * 384 * 2, 256);

    // --- prep: CSR build (single-atomic-pass) + dtype conversions ---
    hipMemsetAsync(cursor, 0, (size_t)NN * 4, stream);
    degree_kernel<<<(NE + 255) / 256, 256, 0, stream>>>(dst, cursor, rank);
    blocksum_kernel<<<NB, 256, 0, stream>>>(cursor, bsum);
    scanb_kernel<<<1, 256, 0, stream>>>(bsum, bscan, csr_row);
    scanfinal_kernel<<<NB, 256, 0, stream>>>(cursor, bscan, csr_row);
    fill_kernel<<<(NE + 255) / 256, 256, 0, stream>>>(src, dst, csr_row, rank, csr_src);
    hipMemsetAsync(p, 0, (size_t)NG * 384 * 4, stream);

    prep_kernel<<<(800000 + 237568 + 255) / 256, 256, 0, stream>>>(
        x, xb,
        c_w1[0], c_w1[1], c_w1[2], c_w2[0], c_w2[1], c_w2[2], lin1_w,
        w1t[0], w1t[1], w1t[2], w2t[0], w2t[1], w2t[2], lin1t);

    const int GATHER_X = (NN + 31) / 32;      // 32 nodes per block (8 waves x 4 nodes)
    const int MLP_BLOCKS = (NN + 63) / 64;

    // layer 1 (K=64): 2 feature passes
    gather_pass_kernel<32><<<dim3(GATHER_X, 2), 512, 0, stream>>>(xb, csr_row, csr_src, agg);
    mlp_mfma_kernel<64, true><<<MLP_BLOCKS, 512, 0, stream>>>(agg, w1t[0], c_b1[0], c_g[0], c_be[0],
                                                              c_m[0], c_v[0], w2t[0], c_b2[0], hA,
                                                              batch, p, 0);

    // layer 2 (K=128): 4 feature passes
    gather_pass_kernel<64><<<dim3(GATHER_X, 4), 512, 0, stream>>>(hA, csr_row, csr_src, agg);
    mlp_mfma_kernel<128, true><<<MLP_BLOCKS, 512, 0, stream>>>(agg, w1t[1], c_b1[1], c_g[1], c_be[1],
                                                               c_m[1], c_v[1], w2t[1], c_b2[1], hB,
                                                               batch, p, 128);

    // layer 3 (K=128): 4 feature passes; output only feeds pooling
    gather_pass_kernel<64><<<dim3(GATHER_X, 4), 512, 0, stream>>>(hB, csr_row, csr_src, agg);
    mlp_mfma_kernel<128, false><<<MLP_BLOCKS, 512, 0, stream>>>(agg, w1t[2], c_b1[2], c_g[2], c_be[2],
                                                                c_m[2], c_v[2], w2t[2], c_b2[2], nullptr,
                                                                batch, p, 256);

    // head: MFMA GEMM + per-wave logits/log_softmax
    head1_kernel<<<dim3(8, 3), 512, 0, stream>>>(p, lin1t, lin1_b, hrelu);
    head2_kernel<<<128, 256, 0, stream>>>(hrelu, lin2_w, lin2_b, out);
}

// Round 9
// 247.623 us; speedup vs baseline: 1.1636x; 1.1636x over previous
//
#include <hip/hip_runtime.h>
#include <math.h>
#include <stdint.h>

static constexpr int NN = 50000;   // nodes
static constexpr int NE = 800000;  // edges
static constexpr int NG = 512;     // graphs
static constexpr int NB = (NN + 255) / 256;  // 196 scan blocks
static constexpr float BNEPS = 1e-5f;

typedef __bf16 bf16x8 __attribute__((ext_vector_type(8)));
typedef __bf16 bf16x2 __attribute__((ext_vector_type(2)));
typedef float f32x4 __attribute__((ext_vector_type(4)));

__device__ __forceinline__ uint32_t pack_bf16(float x, float y) {
    bf16x2 v; v[0] = (__bf16)x; v[1] = (__bf16)y;
    return __builtin_bit_cast(uint32_t, v);
}
__device__ __forceinline__ float2 unpack_bf16(uint32_t u) {
    bf16x2 v = __builtin_bit_cast(bf16x2, u);
    return make_float2((float)v[0], (float)v[1]);
}

// ---------------- CSR build ----------------

// degree + per-edge rank in one pass (rank = position within dst's row)
__global__ void degree_kernel(const int* __restrict__ dst, int* __restrict__ deg,
                              uint16_t* __restrict__ rank) {
    int e = blockIdx.x * blockDim.x + threadIdx.x;
    if (e < NE) rank[e] = (uint16_t)atomicAdd(&deg[dst[e]], 1);
}

// phase A: per-block (256 nodes) sum of degrees
__global__ __launch_bounds__(256) void blocksum_kernel(const int* __restrict__ deg,
                                                       int* __restrict__ bsum) {
    int i = blockIdx.x * 256 + threadIdx.x;
    int v = (i < NN) ? deg[i] : 0;
#pragma unroll
    for (int off = 32; off; off >>= 1) v += __shfl_down(v, off, 64);
    __shared__ int s[4];
    if ((threadIdx.x & 63) == 0) s[threadIdx.x >> 6] = v;
    __syncthreads();
    if (threadIdx.x == 0) bsum[blockIdx.x] = s[0] + s[1] + s[2] + s[3];
}

// phase B: exclusive scan of NB block sums (single small block)
__global__ __launch_bounds__(256) void scanb_kernel(const int* __restrict__ bsum,
                                                    int* __restrict__ bscan,
                                                    int* __restrict__ row_ptr) {
    __shared__ int s[256];
    int t = threadIdx.x;
    int v = (t < NB) ? bsum[t] : 0;
    s[t] = v;
    __syncthreads();
    for (int off = 1; off < 256; off <<= 1) {
        int u = (t >= off) ? s[t - off] : 0;
        __syncthreads();
        s[t] += u;
        __syncthreads();
    }
    if (t < NB) bscan[t] = s[t] - v;  // exclusive
    if (t == NB - 1) row_ptr[NN] = s[t];
}

// phase C: per-block exclusive scan + global offset -> row_ptr
__global__ __launch_bounds__(256) void scanfinal_kernel(const int* __restrict__ deg,
                                                        const int* __restrict__ bscan,
                                                        int* __restrict__ row_ptr) {
    __shared__ int s[256];
    int t = threadIdx.x;
    int i = blockIdx.x * 256 + t;
    int v = (i < NN) ? deg[i] : 0;
    s[t] = v;
    __syncthreads();
    for (int off = 1; off < 256; off <<= 1) {
        int u = (t >= off) ? s[t - off] : 0;
        __syncthreads();
        s[t] += u;
        __syncthreads();
    }
    if (i < NN) row_ptr[i] = bscan[blockIdx.x] + s[t] - v;
}

// atomic-free fill using precomputed rank; cols are u16 (N < 65536)
__global__ void fill_kernel(const int* __restrict__ src, const int* __restrict__ dst,
                            const int* __restrict__ row_ptr, const uint16_t* __restrict__ rank,
                            uint16_t* __restrict__ cols) {
    int e = blockIdx.x * blockDim.x + threadIdx.x;
    if (e < NE) cols[row_ptr[dst[e]] + (int)rank[e]] = (uint16_t)src[e];
}

// ---------------- prep: x fp32->bf16 + all weight transposes, one kernel ----------------

__global__ void prep_kernel(const float* __restrict__ x, __bf16* __restrict__ xb,
                            const float* s0, const float* s1, const float* s2,
                            const float* s3, const float* s4, const float* s5,
                            const float* s6,
                            __bf16* d0, __bf16* d1, __bf16* d2,
                            __bf16* d3, __bf16* d4, __bf16* d5, __bf16* d6) {
    int i = blockIdx.x * blockDim.x + threadIdx.x;
    if (i < 800000) {
        float4 v = *(const float4*)&x[i * 4];
        xb[i * 4 + 0] = (__bf16)v.x;
        xb[i * 4 + 1] = (__bf16)v.y;
        xb[i * 4 + 2] = (__bf16)v.z;
        xb[i * 4 + 3] = (__bf16)v.w;
        return;
    }
    int j = i - 800000;
    if (j < 8192) {
        int l = j;           int n = l / 64,  k = l % 64;  d0[l] = (__bf16)s0[k * 128 + n];
    } else if (j < 24576) {
        int l = j - 8192;    int n = l / 128, k = l % 128; d1[l] = (__bf16)s1[k * 128 + n];
    } else if (j < 40960) {
        int l = j - 24576;   int n = l / 128, k = l % 128; d2[l] = (__bf16)s2[k * 128 + n];
    } else if (j < 57344) {
        int l = j - 40960;   int n = l / 128, k = l % 128; d3[l] = (__bf16)s3[k * 128 + n];
    } else if (j < 73728) {
        int l = j - 57344;   int n = l / 128, k = l % 128; d4[l] = (__bf16)s4[k * 128 + n];
    } else if (j < 90112) {
        int l = j - 73728;   int n = l / 128, k = l % 128; d5[l] = (__bf16)s5[k * 128 + n];
    } else if (j < 237568) {
        int l = j - 90112;   int n = l / 384, k = l % 384; d6[l] = (__bf16)s6[k * 384 + n];
    }
}

// ---------------- gather: agg[n] = in[n] + sum_{j->n} in[j]  (bf16, fp32 accum) ----------------
// one wave per node, 8 waves/block, unroll 8 for memory-level parallelism

__global__ __launch_bounds__(512) void gather64_kernel(const __bf16* __restrict__ in,
                                                       const int* __restrict__ row_ptr,
                                                       const uint16_t* __restrict__ cols,
                                                       __bf16* __restrict__ agg) {
    int node = blockIdx.x * 8 + (threadIdx.x >> 6);
    int lane = threadIdx.x & 63;
    if (node >= NN) return;
    int beg = row_ptr[node], end = row_ptr[node + 1];
    float acc0 = (float)in[(size_t)node * 64 + lane];
    float acc1 = 0.f;
    int i = beg;
    for (; i + 8 <= end; i += 8) {
        int c0 = cols[i], c1 = cols[i + 1], c2 = cols[i + 2], c3 = cols[i + 3];
        int c4 = cols[i + 4], c5 = cols[i + 5], c6 = cols[i + 6], c7 = cols[i + 7];
        float v0 = (float)in[(size_t)c0 * 64 + lane];
        float v1 = (float)in[(size_t)c1 * 64 + lane];
        float v2 = (float)in[(size_t)c2 * 64 + lane];
        float v3 = (float)in[(size_t)c3 * 64 + lane];
        float v4 = (float)in[(size_t)c4 * 64 + lane];
        float v5 = (float)in[(size_t)c5 * 64 + lane];
        float v6 = (float)in[(size_t)c6 * 64 + lane];
        float v7 = (float)in[(size_t)c7 * 64 + lane];
        acc0 += (v0 + v1) + (v2 + v3);
        acc1 += (v4 + v5) + (v6 + v7);
    }
    for (; i < end; ++i) acc0 += (float)in[(size_t)cols[i] * 64 + lane];
    agg[(size_t)node * 64 + lane] = (__bf16)(acc0 + acc1);
}

__global__ __launch_bounds__(512) void gather128_kernel(const __bf16* __restrict__ in,
                                                        const int* __restrict__ row_ptr,
                                                        const uint16_t* __restrict__ cols,
                                                        __bf16* __restrict__ agg) {
    int node = blockIdx.x * 8 + (threadIdx.x >> 6);
    int lane = threadIdx.x & 63;
    if (node >= NN) return;
    const uint32_t* inu = (const uint32_t*)in;
    uint32_t* aggu = (uint32_t*)agg;
    int beg = row_ptr[node], end = row_ptr[node + 1];
    float2 a0 = unpack_bf16(inu[(size_t)node * 64 + lane]);
    float2 a1 = make_float2(0.f, 0.f);
    int i = beg;
    for (; i + 8 <= end; i += 8) {
        int c0 = cols[i], c1 = cols[i + 1], c2 = cols[i + 2], c3 = cols[i + 3];
        int c4 = cols[i + 4], c5 = cols[i + 5], c6 = cols[i + 6], c7 = cols[i + 7];
        uint32_t u0 = inu[(size_t)c0 * 64 + lane];
        uint32_t u1 = inu[(size_t)c1 * 64 + lane];
        uint32_t u2 = inu[(size_t)c2 * 64 + lane];
        uint32_t u3 = inu[(size_t)c3 * 64 + lane];
        uint32_t u4 = inu[(size_t)c4 * 64 + lane];
        uint32_t u5 = inu[(size_t)c5 * 64 + lane];
        uint32_t u6 = inu[(size_t)c6 * 64 + lane];
        uint32_t u7 = inu[(size_t)c7 * 64 + lane];
        float2 v0 = unpack_bf16(u0), v1 = unpack_bf16(u1);
        float2 v2 = unpack_bf16(u2), v3 = unpack_bf16(u3);
        float2 v4 = unpack_bf16(u4), v5 = unpack_bf16(u5);
        float2 v6 = unpack_bf16(u6), v7 = unpack_bf16(u7);
        a0.x += (v0.x + v1.x) + (v2.x + v3.x);
        a0.y += (v0.y + v1.y) + (v2.y + v3.y);
        a1.x += (v4.x + v5.x) + (v6.x + v7.x);
        a1.y += (v4.y + v5.y) + (v6.y + v7.y);
    }
    for (; i < end; ++i) {
        float2 v = unpack_bf16(inu[(size_t)cols[i] * 64 + lane]);
        a0.x += v.x; a0.y += v.y;
    }
    aggu[(size_t)node * 64 + lane] = pack_bf16(a0.x + a1.x, a0.y + a1.y);
}

// ---------------- fused MLP via MFMA + pooling epilogue ----------------
// LDS-shrunk: sW shared between W1/W2 (barrier-separated), sOut overlays sA.
// ~70 KB LDS + launch_bounds(512,4) -> 2 blocks/CU: staging of block B overlaps
// MFMA of block A.
// Overlay safety: last read of sA (stride KP) is phase-1 MFMA, which completes
// before the post-phase-1 barrier; first write of sOut (stride KP2) is the
// phase-2 epilogue, two barriers later. W2 staging overwrites W1 only after the
// post-phase-1 barrier guarantees all W1 reads are done.

template <int K, bool WOUT>
__global__ __launch_bounds__(512, 4) void mlp_mfma_kernel(
    const __bf16* __restrict__ agg,   // [NN][K] bf16
    const __bf16* __restrict__ w1t,   // [128][K] bf16 (transposed)
    const float* __restrict__ b1,
    const float* __restrict__ g, const float* __restrict__ be,
    const float* __restrict__ m, const float* __restrict__ v,
    const __bf16* __restrict__ w2t,   // [128][128] bf16 (transposed)
    const float* __restrict__ b2,
    __bf16* __restrict__ out,         // [NN][128] bf16 (unused if !WOUT)
    const int* __restrict__ batch,    // [NN] sorted graph ids
    float* __restrict__ p,            // [NG][384] pooled accumulator
    int col_off)
{
    constexpr int KP = K + 8;          // sA row stride
    constexpr int KP2 = 136;           // sT / sOut / W2 row stride
    __shared__ alignas(16) __bf16 sAO[64 * KP2];   // sA (KP) then sOut (KP2)
    __shared__ alignas(16) __bf16 sW[128 * KP2];   // W1 (KP) then W2 (KP2)
    __shared__ alignas(16) __bf16 sT[64 * KP2];
    __shared__ int sBatch[64];

    int tid = threadIdx.x;
    int wid = tid >> 6, lane = tid & 63;
    int wr = wid >> 1, wc = wid & 1;
    int l15 = lane & 15, lq = lane >> 4;
    int rowbase = blockIdx.x * 64;

    // stage In tile [64][K] (stride KP)
    for (int idx = tid; idx < 64 * (K / 8); idx += 512) {
        int r = idx / (K / 8), kc = idx % (K / 8);
        int n = rowbase + r;
        uint4 val = make_uint4(0, 0, 0, 0);
        if (n < NN) val = *(const uint4*)&agg[(size_t)n * K + kc * 8];
        *(uint4*)&sAO[r * KP + kc * 8] = val;
    }
    // stage W1 [128][K] (stride KP)
    for (int idx = tid; idx < 128 * (K / 8); idx += 512) {
        int n = idx / (K / 8), kc = idx % (K / 8);
        *(uint4*)&sW[n * KP + kc * 8] = *(const uint4*)&w1t[n * K + kc * 8];
    }
    if (tid < 64) {
        int n = rowbase + tid;
        sBatch[tid] = (n < NN) ? batch[n] : -1;
    }
    __syncthreads();

    // phase 1: T = relu(bn(A @ W1 + b1))
    f32x4 acc[4] = {};
#pragma unroll
    for (int ks = 0; ks < K / 32; ++ks) {
        bf16x8 a = *(const bf16x8*)&sAO[(wr * 16 + l15) * KP + ks * 32 + lq * 8];
#pragma unroll
        for (int nf = 0; nf < 4; ++nf) {
            bf16x8 b = *(const bf16x8*)&sW[(wc * 64 + nf * 16 + l15) * KP + ks * 32 + lq * 8];
            acc[nf] = __builtin_amdgcn_mfma_f32_16x16x32_bf16(a, b, acc[nf], 0, 0, 0);
        }
    }
#pragma unroll
    for (int nf = 0; nf < 4; ++nf) {
        int c = wc * 64 + nf * 16 + l15;
        float sc = g[c] * rsqrtf(v[c] + BNEPS);
        float sh = be[c] + (b1[c] - m[c]) * sc;
#pragma unroll
        for (int r = 0; r < 4; ++r) {
            int row = wr * 16 + lq * 4 + r;
            float t = fmaxf(acc[nf][r] * sc + sh, 0.f);
            sT[row * KP2 + c] = (__bf16)t;
        }
    }
    __syncthreads();   // phase-1 reads of sA/sW complete

    // stage W2 [128][128] (stride KP2), overwriting W1
    for (int idx = tid; idx < 128 * 16; idx += 512) {
        int n = idx >> 4, kc = idx & 15;
        *(uint4*)&sW[n * KP2 + kc * 8] = *(const uint4*)&w2t[n * 128 + kc * 8];
    }
    __syncthreads();

    // phase 2: out = relu(T @ W2 + b2)
    f32x4 acc2[4] = {};
#pragma unroll
    for (int ks = 0; ks < 4; ++ks) {
        bf16x8 a = *(const bf16x8*)&sT[(wr * 16 + l15) * KP2 + ks * 32 + lq * 8];
#pragma unroll
        for (int nf = 0; nf < 4; ++nf) {
            bf16x8 b = *(const bf16x8*)&sW[(wc * 64 + nf * 16 + l15) * KP2 + ks * 32 + lq * 8];
            acc2[nf] = __builtin_amdgcn_mfma_f32_16x16x32_bf16(a, b, acc2[nf], 0, 0, 0);
        }
    }
    // epilogue -> sOut (overlays the dead sA region, stride KP2)
#pragma unroll
    for (int nf = 0; nf < 4; ++nf) {
        int c = wc * 64 + nf * 16 + l15;
        float bb = b2[c];
#pragma unroll
        for (int r = 0; r < 4; ++r) {
            int row = wr * 16 + lq * 4 + r;
            float o = fmaxf(acc2[nf][r] + bb, 0.f);
            sAO[row * KP2 + c] = (__bf16)o;
        }
    }
    __syncthreads();

    if constexpr (WOUT) {
        for (int idx = tid; idx < 64 * 16; idx += 512) {
            int r = idx >> 4, kc = idx & 15;
            int n = rowbase + r;
            if (n < NN)
                *(uint4*)&out[(size_t)n * 128 + kc * 8] = *(const uint4*)&sAO[r * KP2 + kc * 8];
        }
    }

    // fused pooling: 4 row-chunks x 128 features; batch sorted -> run accumulation
    {
        int f = tid & 127;
        int chunk = tid >> 7;
        float pacc = 0.f;
        int cur = -1;
#pragma unroll
        for (int i = 0; i < 16; ++i) {
            int row = chunk * 16 + i;
            int b = sBatch[row];
            if (b < 0) break;
            if (b != cur) {
                if (cur >= 0) atomicAdd(&p[cur * 384 + col_off + f], pacc);
                pacc = 0.f;
                cur = b;
            }
            pacc += (float)sAO[row * KP2 + f];
        }
        if (cur >= 0) atomicAdd(&p[cur * 384 + col_off + f], pacc);
    }
}

// ---------------- head stage 1: hrelu = relu(p @ lin1 + b)  via MFMA ----------------

__global__ __launch_bounds__(512, 1) void head1_kernel(const float* __restrict__ p,
                                                       const __bf16* __restrict__ lin1t,
                                                       const float* __restrict__ b1,
                                                       float* __restrict__ hrelu) {
    constexpr int KPA = 392;   // 384 + 8
    constexpr int KPW = 136;   // 128 + 8
    __shared__ alignas(16) __bf16 sA[64 * KPA];
    __shared__ alignas(16) __bf16 sW[128 * KPW];

    int tid = threadIdx.x;
    int wid = tid >> 6, lane = tid & 63;
    int wr = wid >> 1, wc = wid & 1;
    int l15 = lane & 15, lq = lane >> 4;
    int rowbase = blockIdx.x * 64;     // 0..448
    int colbase = blockIdx.y * 128;    // 0, 128, 256

    for (int idx = tid; idx < 64 * 48; idx += 512) {
        int r = idx / 48, kc = idx % 48;
        const float* srcp = &p[(rowbase + r) * 384 + kc * 8];
        float4 v0 = *(const float4*)srcp;
        float4 v1 = *(const float4*)(srcp + 4);
        bf16x8 o;
        o[0] = (__bf16)v0.x; o[1] = (__bf16)v0.y; o[2] = (__bf16)v0.z; o[3] = (__bf16)v0.w;
        o[4] = (__bf16)v1.x; o[5] = (__bf16)v1.y; o[6] = (__bf16)v1.z; o[7] = (__bf16)v1.w;
        *(bf16x8*)&sA[r * KPA + kc * 8] = o;
    }

    f32x4 acc[4] = {};
#pragma unroll
    for (int kchunk = 0; kchunk < 3; ++kchunk) {
        for (int idx = tid; idx < 128 * 16; idx += 512) {
            int n = idx >> 4, kc = idx & 15;
            *(uint4*)&sW[n * KPW + kc * 8] =
                *(const uint4*)&lin1t[(colbase + n) * 384 + kchunk * 128 + kc * 8];
        }
        __syncthreads();
#pragma unroll
        for (int ks = 0; ks < 4; ++ks) {
            bf16x8 a = *(const bf16x8*)&sA[(wr * 16 + l15) * KPA + kchunk * 128 + ks * 32 + lq * 8];
#pragma unroll
            for (int nf = 0; nf < 4; ++nf) {
                bf16x8 b = *(const bf16x8*)&sW[(wc * 64 + nf * 16 + l15) * KPW + ks * 32 + lq * 8];
                acc[nf] = __builtin_amdgcn_mfma_f32_16x16x32_bf16(a, b, acc[nf], 0, 0, 0);
            }
        }
        __syncthreads();
    }
#pragma unroll
    for (int nf = 0; nf < 4; ++nf) {
        int col = colbase + wc * 64 + nf * 16 + l15;
        float bb = b1[col];
#pragma unroll
        for (int r = 0; r < 4; ++r) {
            int row = rowbase + wr * 16 + lq * 4 + r;
            hrelu[row * 384 + col] = fmaxf(acc[nf][r] + bb, 0.f);
        }
    }
}

// ---------------- head stage 2: logits + log_softmax, one wave per graph ----------------

__global__ __launch_bounds__(256) void head2_kernel(const float* __restrict__ hrelu,
                                                    const float* __restrict__ w2,   // [384][10]
                                                    const float* __restrict__ b2,
                                                    float* __restrict__ out) {
    int wid = threadIdx.x >> 6, lane = threadIdx.x & 63;
    int gidx = blockIdx.x * 4 + wid;   // grid 128 -> 512 graphs
    const float* hr = &hrelu[gidx * 384 + lane * 6];
    float h[6];
#pragma unroll
    for (int u = 0; u < 6; ++u) h[u] = hr[u];
    float logit[10];
#pragma unroll
    for (int c = 0; c < 10; ++c) {
        float s = 0.f;
#pragma unroll
        for (int u = 0; u < 6; ++u) s = fmaf(h[u], w2[(lane * 6 + u) * 10 + c], s);
#pragma unroll
        for (int off = 32; off; off >>= 1) s += __shfl_xor(s, off, 64);
        logit[c] = s + b2[c];
    }
    float mx = logit[0];
#pragma unroll
    for (int c = 1; c < 10; ++c) mx = fmaxf(mx, logit[c]);
    float se = 0.f;
#pragma unroll
    for (int c = 0; c < 10; ++c) se += expf(logit[c] - mx);
    float lse = logf(se);
    float val = 0.f;
#pragma unroll
    for (int c = 0; c < 10; ++c) if (lane == c) val = logit[c];
    if (lane < 10) out[gidx * 10 + lane] = val - mx - lse;
}

// ---------------- launch ----------------

static inline char* align_up(char* ptr, size_t a) {
    return (char*)(((uintptr_t)ptr + a - 1) & ~(uintptr_t)(a - 1));
}

extern "C" void kernel_launch(void* const* d_in, const int* in_sizes, int n_in,
                              void* d_out, int out_size, void* d_ws, size_t ws_size,
                              hipStream_t stream) {
    const float* x = (const float*)d_in[0];
    const int* ei = (const int*)d_in[1];
    const int* batch = (const int*)d_in[2];
    const float* c_w1[3], *c_b1[3], *c_g[3], *c_be[3], *c_m[3], *c_v[3], *c_w2[3], *c_b2[3];
    for (int i = 0; i < 3; ++i) {
        int base = 3 + i * 8;
        c_w1[i] = (const float*)d_in[base + 0];
        c_b1[i] = (const float*)d_in[base + 1];
        c_g[i]  = (const float*)d_in[base + 2];
        c_be[i] = (const float*)d_in[base + 3];
        c_m[i]  = (const float*)d_in[base + 4];
        c_v[i]  = (const float*)d_in[base + 5];
        c_w2[i] = (const float*)d_in[base + 6];
        c_b2[i] = (const float*)d_in[base + 7];
    }
    const float* lin1_w = (const float*)d_in[27];
    const float* lin1_b = (const float*)d_in[28];
    const float* lin2_w = (const float*)d_in[29];
    const float* lin2_b = (const float*)d_in[30];
    const int* src = ei;
    const int* dst = ei + NE;
    float* out = (float*)d_out;

    // workspace carve
    char* ws = (char*)d_ws;
    __bf16* xb  = (__bf16*)ws; ws = align_up(ws + (size_t)NN * 64 * 2, 256);
    __bf16* agg = (__bf16*)ws; ws = align_up(ws + (size_t)NN * 128 * 2, 256);
    __bf16* hA  = (__bf16*)ws; ws = align_up(ws + (size_t)NN * 128 * 2, 256);
    __bf16* hB  = (__bf16*)ws; ws = align_up(ws + (size_t)NN * 128 * 2, 256);
    float* p    = (float*)ws;  ws = align_up(ws + (size_t)NG * 384 * 4, 256);
    float* hrelu = (float*)ws; ws = align_up(ws + (size_t)NG * 384 * 4, 256);
    int* csr_row = (int*)ws;   ws = align_up(ws + (size_t)(NN + 1) * 4, 256);
    int* cursor  = (int*)ws;   ws = align_up(ws + (size_t)NN * 4, 256);
    uint16_t* csr_src = (uint16_t*)ws; ws = align_up(ws + (size_t)NE * 2, 256);
    uint16_t* rank    = (uint16_t*)ws; ws = align_up(ws + (size_t)NE * 2, 256);
    int* bsum    = (int*)ws;   ws = align_up(ws + (size_t)NB * 4, 256);
    int* bscan   = (int*)ws;   ws = align_up(ws + (size_t)NB * 4, 256);
    __bf16* w1t[3]; __bf16* w2t[3];
    for (int i = 0; i < 3; ++i) {
        int K = (i == 0) ? 64 : 128;
        w1t[i] = (__bf16*)ws; ws = align_up(ws + (size_t)128 * K * 2, 256);
        w2t[i] = (__bf16*)ws; ws = align_up(ws + (size_t)128 * 128 * 2, 256);
    }
    __bf16* lin1t = (__bf16*)ws; ws = align_up(ws + (size_t)384 * 384 * 2, 256);

    // --- prep: CSR build (single-atomic-pass) + dtype conversions ---
    hipMemsetAsync(cursor, 0, (size_t)NN * 4, stream);
    degree_kernel<<<(NE + 255) / 256, 256, 0, stream>>>(dst, cursor, rank);
    blocksum_kernel<<<NB, 256, 0, stream>>>(cursor, bsum);
    scanb_kernel<<<1, 256, 0, stream>>>(bsum, bscan, csr_row);
    scanfinal_kernel<<<NB, 256, 0, stream>>>(cursor, bscan, csr_row);
    fill_kernel<<<(NE + 255) / 256, 256, 0, stream>>>(src, dst, csr_row, rank, csr_src);
    hipMemsetAsync(p, 0, (size_t)NG * 384 * 4, stream);

    prep_kernel<<<(800000 + 237568 + 255) / 256, 256, 0, stream>>>(
        x, xb,
        c_w1[0], c_w1[1], c_w1[2], c_w2[0], c_w2[1], c_w2[2], lin1_w,
        w1t[0], w1t[1], w1t[2], w2t[0], w2t[1], w2t[2], lin1t);

    const int GATHER_BLOCKS = (NN + 7) / 8;   // 8 waves/block, one wave per node
    const int MLP_BLOCKS = (NN + 63) / 64;

    // layer 1 (K=64)
    gather64_kernel<<<GATHER_BLOCKS, 512, 0, stream>>>(xb, csr_row, csr_src, agg);
    mlp_mfma_kernel<64, true><<<MLP_BLOCKS, 512, 0, stream>>>(agg, w1t[0], c_b1[0], c_g[0], c_be[0],
                                                              c_m[0], c_v[0], w2t[0], c_b2[0], hA,
                                                              batch, p, 0);

    // layer 2 (K=128)
    gather128_kernel<<<GATHER_BLOCKS, 512, 0, stream>>>(hA, csr_row, csr_src, agg);
    mlp_mfma_kernel<128, true><<<MLP_BLOCKS, 512, 0, stream>>>(agg, w1t[1], c_b1[1], c_g[1], c_be[1],
                                                               c_m[1], c_v[1], w2t[1], c_b2[1], hB,
                                                               batch, p, 128);

    // layer 3 (K=128) — output only feeds pooling, skip global store
    gather128_kernel<<<GATHER_BLOCKS, 512, 0, stream>>>(hB, csr_row, csr_src, agg);
    mlp_mfma_kernel<128, false><<<MLP_BLOCKS, 512, 0, stream>>>(agg, w1t[2], c_b1[2], c_g[2], c_be[2],
                                                                c_m[2], c_v[2], w2t[2], c_b2[2], nullptr,
                                                                batch, p, 256);

    // head: MFMA GEMM + per-wave logits/log_softmax
    head1_kernel<<<dim3(8, 3), 512, 0, stream>>>(p, lin1t, lin1_b, hrelu);
    head2_kernel<<<128, 256, 0, stream>>>(hrelu, lin2_w, lin2_b, out);
}